// Round 1
// baseline (262.086 us; speedup 1.0000x reference)
//
#include <hip/hip_runtime.h>
#include <hip/hip_bf16.h>
#include <stdint.h>

// ---------------------------------------------------------------------------
// LayerNormLSTMCell: B=4096, I=H=1024, 4H=4096
//  hi = LN(input @ w_i2h + b_i2h; g_i2h, be_i2h)        [B,4H]
//  hh = LN(h_prev @ w_h2h + b_h2h; g_h2h, be_h2h)       [B,4H]
//  i,f,u,o = split(hi+hh, 4)
//  c = LN(c_prev*sigm(f+1) + tanh(u)*sigm(i); g_c,be_c) [B,H]
//  h = sigm(o)*tanh(c)
// LN: mean, UNBIASED std (ddof=1), divide by (std + 1e-6)
// ---------------------------------------------------------------------------

#define BDIM 4096
#define KDIM 1024
#define NDIM 4096
#define EPSV 1e-6f

typedef float f32x4 __attribute__((ext_vector_type(4)));
typedef __bf16 bf16x8 __attribute__((ext_vector_type(8)));

__device__ inline unsigned short f2bf(float f) {
    unsigned u = __builtin_bit_cast(unsigned, f);
    u += 0x7FFFu + ((u >> 16) & 1u);   // round-to-nearest-even
    return (unsigned short)(u >> 16);
}
__device__ inline float bf2f(unsigned short u) {
    return __builtin_bit_cast(float, (unsigned)u << 16);
}
__device__ inline float sigm(float x) {
    return 1.0f / (1.0f + __expf(-x));
}

// async global->LDS, 16B per lane. lds ptr must be wave-uniform.
__device__ inline void async16(const unsigned short* g, unsigned short* lds) {
    __builtin_amdgcn_global_load_lds(
        (const __attribute__((address_space(1))) void*)g,
        (__attribute__((address_space(3))) void*)lds,
        16, 0, 0);
}

// ---------------------------------------------------------------------------
// cast f32 -> bf16 (4 elems/thread)
// ---------------------------------------------------------------------------
__global__ void cast_bf16(const float* __restrict__ src, unsigned short* __restrict__ dst, int n) {
    int i = (blockIdx.x * blockDim.x + threadIdx.x) * 4;
    if (i < n) {
        float4 v = *(const float4*)(src + i);
        ushort4 o;
        o.x = f2bf(v.x); o.y = f2bf(v.y); o.z = f2bf(v.z); o.w = f2bf(v.w);
        *(ushort4*)(dst + i) = o;
    }
}

// ---------------------------------------------------------------------------
// transpose + cast: src f32 [R][C] -> dst bf16 [C][R]
// ---------------------------------------------------------------------------
__global__ void transpose_cast(const float* __restrict__ src, unsigned short* __restrict__ dst,
                               int R, int C) {
    __shared__ float tile[32][33];
    int c0 = blockIdx.x * 32, r0 = blockIdx.y * 32;
    int tx = threadIdx.x, ty = threadIdx.y; // 32 x 8
    #pragma unroll
    for (int i = 0; i < 32; i += 8)
        tile[ty + i][tx] = src[(size_t)(r0 + ty + i) * C + c0 + tx];
    __syncthreads();
    #pragma unroll
    for (int i = 0; i < 32; i += 8)
        dst[(size_t)(c0 + ty + i) * R + r0 + tx] = f2bf(tile[tx][ty + i]);
}

// ---------------------------------------------------------------------------
// GEMM: C[m][n] = sum_k A[m][k] * Bt[n][k] + bias[n]   (bf16 in, bf16 out)
// M=4096 N=4096 K=1024. 128x128 tile, BK=32, 4 waves, 4x4 16x16x32 MFMA/wave.
// blockIdx.z selects problem (i2h vs h2h).
// ---------------------------------------------------------------------------
__global__ __launch_bounds__(256) void gemm_bias_bf16(
    const unsigned short* __restrict__ A0, const unsigned short* __restrict__ B0,
    const float* __restrict__ bias0, unsigned short* __restrict__ C0,
    const unsigned short* __restrict__ A1, const unsigned short* __restrict__ B1,
    const float* __restrict__ bias1, unsigned short* __restrict__ C1)
{
    const unsigned short* A  = blockIdx.z ? A1 : A0;
    const unsigned short* Bt = blockIdx.z ? B1 : B0;
    const float* bias        = blockIdx.z ? bias1 : bias0;
    unsigned short* C        = blockIdx.z ? C1 : C0;

    __shared__ __align__(16) unsigned short Als[128 * 32];
    __shared__ __align__(16) unsigned short Bls[128 * 32];

    const int tid  = threadIdx.x;
    const int wid  = tid >> 6;
    const int lane = tid & 63;
    const int bm = blockIdx.x, bn = blockIdx.y;

    const int wm = (wid >> 1) * 64;   // wave row offset in tile
    const int wn = (wid & 1) * 64;    // wave col offset in tile

    f32x4 acc[4][4] = {};

    // staging: issue i covers tile rows [i*64, i*64+64); this thread handles
    // row = i*64 + wid*16 + lane/4, cols (lane&3)*8 .. +8
    const int srow = wid * 16 + (lane >> 2);
    const int scol = (lane & 3) * 8;
    const unsigned short* Abase = A  + (size_t)(bm * 128 + srow) * KDIM + scol;
    const unsigned short* Bbase = Bt + (size_t)(bn * 128 + srow) * KDIM + scol;
    unsigned short* AldsU = Als + wid * 512;   // wave-uniform, +lane*8 elems by HW
    unsigned short* BldsU = Bls + wid * 512;

    // fragment base pointers
    const unsigned short* a_ptr = &Als[(wm + (lane & 15)) * 32 + (lane >> 4) * 8];
    const unsigned short* b_ptr = &Bls[(wn + (lane & 15)) * 32 + (lane >> 4) * 8];

    for (int k0 = 0; k0 < KDIM; k0 += 32) {
        async16(Abase + k0,                     AldsU);
        async16(Abase + k0 + (size_t)64 * KDIM, AldsU + 2048);
        async16(Bbase + k0,                     BldsU);
        async16(Bbase + k0 + (size_t)64 * KDIM, BldsU + 2048);
        __syncthreads();

        bf16x8 af[4], bfv[4];
        #pragma unroll
        for (int mi = 0; mi < 4; ++mi) af[mi]  = *(const bf16x8*)(a_ptr + mi * 16 * 32);
        #pragma unroll
        for (int ni = 0; ni < 4; ++ni) bfv[ni] = *(const bf16x8*)(b_ptr + ni * 16 * 32);

        #pragma unroll
        for (int mi = 0; mi < 4; ++mi)
            #pragma unroll
            for (int ni = 0; ni < 4; ++ni)
                acc[mi][ni] = __builtin_amdgcn_mfma_f32_16x16x32_bf16(
                    af[mi], bfv[ni], acc[mi][ni], 0, 0, 0);
        __syncthreads();
    }

    // epilogue: lane holds D[row=(lane>>4)*4+r][col=lane&15] per 16x16 tile
    const int rb = wm + (lane >> 4) * 4;
    const int cb = wn + (lane & 15);
    float bv[4];
    #pragma unroll
    for (int ni = 0; ni < 4; ++ni) bv[ni] = bias[bn * 128 + cb + ni * 16];
    #pragma unroll
    for (int mi = 0; mi < 4; ++mi) {
        #pragma unroll
        for (int r = 0; r < 4; ++r) {
            size_t grow = (size_t)(bm * 128 + rb + mi * 16 + r) * NDIM;
            #pragma unroll
            for (int ni = 0; ni < 4; ++ni)
                C[grow + bn * 128 + cb + ni * 16] = f2bf(acc[mi][ni][r] + bv[ni]);
        }
    }
}

// ---------------------------------------------------------------------------
// block reduction of 4 floats across 256 threads (4 waves)
// ---------------------------------------------------------------------------
__device__ inline float4 block_reduce4(float a, float b, float c, float d, float* sm) {
    #pragma unroll
    for (int off = 32; off > 0; off >>= 1) {
        a += __shfl_down(a, off, 64);
        b += __shfl_down(b, off, 64);
        c += __shfl_down(c, off, 64);
        d += __shfl_down(d, off, 64);
    }
    int wid = threadIdx.x >> 6, lane = threadIdx.x & 63;
    __syncthreads();   // protect sm reuse
    if (lane == 0) {
        sm[wid * 4 + 0] = a; sm[wid * 4 + 1] = b;
        sm[wid * 4 + 2] = c; sm[wid * 4 + 3] = d;
    }
    __syncthreads();
    float4 r;
    r.x = sm[0] + sm[4] + sm[8]  + sm[12];
    r.y = sm[1] + sm[5] + sm[9]  + sm[13];
    r.z = sm[2] + sm[6] + sm[10] + sm[14];
    r.w = sm[3] + sm[7] + sm[11] + sm[15];
    return r;
}

// ---------------------------------------------------------------------------
// fused LN(hi) + LN(hh) + gates + LN(cell) + outputs. One block per row.
// thread t handles cols q*1024 + t*4 .. +4 for q=0..3 (the 4 gates align).
// ---------------------------------------------------------------------------
__global__ __launch_bounds__(256) void ln_gates(
    const unsigned short* __restrict__ hi_pre, const unsigned short* __restrict__ hh_pre,
    const float* __restrict__ c_prev,
    const float* __restrict__ g1, const float* __restrict__ be1,
    const float* __restrict__ g2, const float* __restrict__ be2,
    const float* __restrict__ gc, const float* __restrict__ bec,
    float* __restrict__ h_out, float* __restrict__ c_out)
{
    __shared__ float sm[16];
    const int b = blockIdx.x, t = threadIdx.x;
    const unsigned short* hir = hi_pre + (size_t)b * NDIM;
    const unsigned short* hhr = hh_pre + (size_t)b * NDIM;

    float xi[4][4], xh[4][4];
    float s1 = 0.f, ss1 = 0.f, s2 = 0.f, ss2 = 0.f;
    #pragma unroll
    for (int q = 0; q < 4; ++q) {
        int col = q * 1024 + t * 4;
        ushort4 ui = *(const ushort4*)(hir + col);
        ushort4 uh = *(const ushort4*)(hhr + col);
        xi[q][0] = bf2f(ui.x); xi[q][1] = bf2f(ui.y); xi[q][2] = bf2f(ui.z); xi[q][3] = bf2f(ui.w);
        xh[q][0] = bf2f(uh.x); xh[q][1] = bf2f(uh.y); xh[q][2] = bf2f(uh.z); xh[q][3] = bf2f(uh.w);
        #pragma unroll
        for (int j = 0; j < 4; ++j) {
            s1 += xi[q][j]; ss1 += xi[q][j] * xi[q][j];
            s2 += xh[q][j]; ss2 += xh[q][j] * xh[q][j];
        }
    }
    float4 red = block_reduce4(s1, ss1, s2, ss2, sm);
    const float n1 = (float)NDIM;
    float m1 = red.x / n1;
    float v1 = (red.y - n1 * m1 * m1) / (n1 - 1.f);
    float r1 = 1.0f / (sqrtf(fmaxf(v1, 0.f)) + EPSV);
    float m2 = red.z / n1;
    float v2 = (red.w - n1 * m2 * m2) / (n1 - 1.f);
    float r2 = 1.0f / (sqrtf(fmaxf(v2, 0.f)) + EPSV);

    // gates
    float gate[4][4];
    #pragma unroll
    for (int q = 0; q < 4; ++q) {
        int col = q * 1024 + t * 4;
        float4 G1 = *(const float4*)(g1 + col);
        float4 B1 = *(const float4*)(be1 + col);
        float4 G2 = *(const float4*)(g2 + col);
        float4 B2 = *(const float4*)(be2 + col);
        gate[q][0] = G1.x * (xi[q][0] - m1) * r1 + B1.x + G2.x * (xh[q][0] - m2) * r2 + B2.x;
        gate[q][1] = G1.y * (xi[q][1] - m1) * r1 + B1.y + G2.y * (xh[q][1] - m2) * r2 + B2.y;
        gate[q][2] = G1.z * (xi[q][2] - m1) * r1 + B1.z + G2.z * (xh[q][2] - m2) * r2 + B2.z;
        gate[q][3] = G1.w * (xi[q][3] - m1) * r1 + B1.w + G2.w * (xh[q][3] - m2) * r2 + B2.w;
    }

    float4 cp = *(const float4*)(c_prev + (size_t)b * 1024 + t * 4);
    float cpv[4] = {cp.x, cp.y, cp.z, cp.w};
    float a[4], og[4];
    float s3 = 0.f, ss3 = 0.f;
    #pragma unroll
    for (int j = 0; j < 4; ++j) {
        float ig = gate[0][j], fg = gate[1][j], ug = gate[2][j];
        og[j] = gate[3][j];
        a[j] = cpv[j] * sigm(fg + 1.0f) + tanhf(ug) * sigm(ig);
        s3 += a[j]; ss3 += a[j] * a[j];
    }
    float4 red2 = block_reduce4(s3, ss3, 0.f, 0.f, sm);
    const float n3 = 1024.f;
    float m3 = red2.x / n3;
    float v3 = (red2.y - n3 * m3 * m3) / (n3 - 1.f);
    float r3 = 1.0f / (sqrtf(fmaxf(v3, 0.f)) + EPSV);

    int colh = t * 4;
    float4 GC = *(const float4*)(gc + colh);
    float4 BC = *(const float4*)(bec + colh);
    float gcv[4] = {GC.x, GC.y, GC.z, GC.w};
    float bcv[4] = {BC.x, BC.y, BC.z, BC.w};
    float4 hv, cv;
    float cj[4], hj[4];
    #pragma unroll
    for (int j = 0; j < 4; ++j) {
        cj[j] = gcv[j] * (a[j] - m3) * r3 + bcv[j];
        hj[j] = sigm(og[j]) * tanhf(cj[j]);
    }
    hv.x = hj[0]; hv.y = hj[1]; hv.z = hj[2]; hv.w = hj[3];
    cv.x = cj[0]; cv.y = cj[1]; cv.z = cj[2]; cv.w = cj[3];
    *(float4*)(h_out + (size_t)b * 1024 + colh) = hv;
    *(float4*)(c_out + (size_t)b * 1024 + colh) = cv;
}

// ---------------------------------------------------------------------------
extern "C" void kernel_launch(void* const* d_in, const int* in_sizes, int n_in,
                              void* d_out, int out_size, void* d_ws, size_t ws_size,
                              hipStream_t stream) {
    const float* input  = (const float*)d_in[0];
    const float* h_prev = (const float*)d_in[1];
    const float* c_prev = (const float*)d_in[2];
    const float* w_i2h  = (const float*)d_in[3];
    const float* b_i2h  = (const float*)d_in[4];
    const float* w_h2h  = (const float*)d_in[5];
    const float* b_h2h  = (const float*)d_in[6];
    const float* g_i2h  = (const float*)d_in[7];
    const float* be_i2h = (const float*)d_in[8];
    const float* g_h2h  = (const float*)d_in[9];
    const float* be_h2h = (const float*)d_in[10];
    const float* g_c    = (const float*)d_in[11];
    const float* be_c   = (const float*)d_in[12];

    const size_t MK = (size_t)BDIM * KDIM;       // 4M
    const size_t MN = (size_t)BDIM * NDIM;       // 16M

    unsigned short* inA    = (unsigned short*)d_ws;
    unsigned short* inH    = inA + MK;
    unsigned short* w1T    = inH + MK;           // [N][K]
    unsigned short* w2T    = w1T + MK;
    unsigned short* hi_pre = w2T + MK;           // [B][4H] bf16
    unsigned short* hh_pre = hi_pre + MN;        // total 96 MB

    float* h_out = (float*)d_out;
    float* c_out = h_out + (size_t)BDIM * 1024;

    cast_bf16<<<4096, 256, 0, stream>>>(input,  inA, (int)MK);
    cast_bf16<<<4096, 256, 0, stream>>>(h_prev, inH, (int)MK);
    transpose_cast<<<dim3(NDIM / 32, KDIM / 32), dim3(32, 8), 0, stream>>>(w_i2h, w1T, KDIM, NDIM);
    transpose_cast<<<dim3(NDIM / 32, KDIM / 32), dim3(32, 8), 0, stream>>>(w_h2h, w2T, KDIM, NDIM);

    gemm_bias_bf16<<<dim3(32, 32, 2), 256, 0, stream>>>(
        inA, w1T, b_i2h, hi_pre, inH, w2T, b_h2h, hh_pre);

    ln_gates<<<4096, 256, 0, stream>>>(
        hi_pre, hh_pre, c_prev, g_i2h, be_i2h, g_h2h, be_h2h, g_c, be_c, h_out, c_out);
}

// Round 2
// 257.957 us; speedup vs baseline: 1.0160x; 1.0160x over previous
//
#include <hip/hip_runtime.h>
#include <hip/hip_bf16.h>
#include <stdint.h>

// ---------------------------------------------------------------------------
// LayerNormLSTMCell: B=4096, I=H=1024, 4H=4096
//  hi = LN(input @ w_i2h + b_i2h; g_i2h, be_i2h)        [B,4H]
//  hh = LN(h_prev @ w_h2h + b_h2h; g_h2h, be_h2h)       [B,4H]
//  i,f,u,o = split(hi+hh, 4)
//  c = LN(c_prev*sigm(f+1) + tanh(u)*sigm(i); g_c,be_c) [B,H]
//  h = sigm(o)*tanh(c)
// LN: mean, UNBIASED std (ddof=1), divide by (std + 1e-6)
// ---------------------------------------------------------------------------

#define BDIM 4096
#define KDIM 1024
#define NDIM 4096
#define EPSV 1e-6f

typedef float f32x4 __attribute__((ext_vector_type(4)));
typedef __bf16 bf16x8 __attribute__((ext_vector_type(8)));

__device__ inline unsigned short f2bf(float f) {
    unsigned u = __builtin_bit_cast(unsigned, f);
    u += 0x7FFFu + ((u >> 16) & 1u);   // round-to-nearest-even
    return (unsigned short)(u >> 16);
}
__device__ inline float bf2f(unsigned short u) {
    return __builtin_bit_cast(float, (unsigned)u << 16);
}
__device__ inline float sigm(float x) {
    return 1.0f / (1.0f + __expf(-x));
}
// fast tanh: 1 - 2/(e^{2x}+1); saturates correctly at +-inf
__device__ inline float ftanh(float x) {
    return 1.0f - 2.0f / (__expf(2.0f * x) + 1.0f);
}

// async global->LDS, 16B per lane. lds ptr must be wave-uniform.
__device__ inline void async16(const unsigned short* g, unsigned short* lds) {
    __builtin_amdgcn_global_load_lds(
        (const __attribute__((address_space(1))) void*)g,
        (__attribute__((address_space(3))) void*)lds,
        16, 0, 0);
}

// ---------------------------------------------------------------------------
// cast f32 -> bf16 (4 elems/thread); z selects src/dst pair
// ---------------------------------------------------------------------------
__global__ void cast_bf16(const float* __restrict__ s0, unsigned short* __restrict__ d0,
                          const float* __restrict__ s1, unsigned short* __restrict__ d1, int n) {
    const float* src = blockIdx.z ? s1 : s0;
    unsigned short* dst = blockIdx.z ? d1 : d0;
    int i = (blockIdx.x * blockDim.x + threadIdx.x) * 4;
    if (i < n) {
        float4 v = *(const float4*)(src + i);
        ushort4 o;
        o.x = f2bf(v.x); o.y = f2bf(v.y); o.z = f2bf(v.z); o.w = f2bf(v.w);
        *(ushort4*)(dst + i) = o;
    }
}

// ---------------------------------------------------------------------------
// transpose + cast: src f32 [R][C] -> dst bf16 [C][R]; z selects pair
// ---------------------------------------------------------------------------
__global__ void transpose_cast(const float* __restrict__ s0, unsigned short* __restrict__ d0,
                               const float* __restrict__ s1, unsigned short* __restrict__ d1,
                               int R, int C) {
    const float* src = blockIdx.z ? s1 : s0;
    unsigned short* dst = blockIdx.z ? d1 : d0;
    __shared__ float tile[32][33];
    int c0 = blockIdx.x * 32, r0 = blockIdx.y * 32;
    int tx = threadIdx.x, ty = threadIdx.y; // 32 x 8
    #pragma unroll
    for (int i = 0; i < 32; i += 8)
        tile[ty + i][tx] = src[(size_t)(r0 + ty + i) * C + c0 + tx];
    __syncthreads();
    #pragma unroll
    for (int i = 0; i < 32; i += 8)
        dst[(size_t)(c0 + ty + i) * R + r0 + tx] = f2bf(tile[tx][ty + i]);
}

// ---------------------------------------------------------------------------
// GEMM: C[m][n] = sum_k A[m][k] * Bt[n][k] + bias[n]   (bf16 in, bf16 out)
// M=4096 N=4096 K=1024. 128x128 tile, BK=32, 4 waves, 4x4 16x16x32 MFMA/wave.
// LDS column-segment XOR swizzle (seg' = seg ^ ((row>>1)&3)) applied on the
// GLOBAL source side of global_load_lds (dest is fixed base+lane*16B), undone
// on the ds_read side -> 2-way bank aliasing only (free).
// blockIdx.z selects problem (i2h vs h2h).
// ---------------------------------------------------------------------------
__global__ __launch_bounds__(256) void gemm_bias_bf16(
    const unsigned short* __restrict__ A0, const unsigned short* __restrict__ B0,
    const float* __restrict__ bias0, unsigned short* __restrict__ C0,
    const unsigned short* __restrict__ A1, const unsigned short* __restrict__ B1,
    const float* __restrict__ bias1, unsigned short* __restrict__ C1)
{
    const unsigned short* A  = blockIdx.z ? A1 : A0;
    const unsigned short* Bt = blockIdx.z ? B1 : B0;
    const float* bias        = blockIdx.z ? bias1 : bias0;
    unsigned short* C        = blockIdx.z ? C1 : C0;

    __shared__ __align__(16) unsigned short Als[128 * 32];
    __shared__ __align__(16) unsigned short Bls[128 * 32];

    const int tid  = threadIdx.x;
    const int wid  = tid >> 6;
    const int lane = tid & 63;
    const int bm = blockIdx.x, bn = blockIdx.y;

    const int wm = (wid >> 1) * 64;   // wave row offset in tile
    const int wn = (wid & 1) * 64;    // wave col offset in tile

    f32x4 acc[4][4] = {};

    // staging: this thread covers tile row srow (per 64-row half), 16B chunk.
    // Global k-segment is XOR-swizzled by row so LDS bank groups spread.
    const int srow = wid * 16 + (lane >> 2);
    const int sseg = (lane & 3) ^ ((srow >> 1) & 3);
    const int scol = sseg * 8;
    const unsigned short* Abase = A  + (size_t)(bm * 128 + srow) * KDIM + scol;
    const unsigned short* Bbase = Bt + (size_t)(bn * 128 + srow) * KDIM + scol;
    unsigned short* AldsU = Als + wid * 512;   // wave-uniform, +lane*8 elems by HW
    unsigned short* BldsU = Bls + wid * 512;

    // fragment base pointers (undo swizzle): row = wm/wn + (lane&15),
    // physical seg = (lane>>4) ^ ((row>>1)&3); wm,mi*16 don't affect (row>>1)&3
    const int fseg = ((lane >> 4) ^ (((lane & 15) >> 1) & 3)) * 8;
    const unsigned short* a_ptr = &Als[(wm + (lane & 15)) * 32 + fseg];
    const unsigned short* b_ptr = &Bls[(wn + (lane & 15)) * 32 + fseg];

    for (int k0 = 0; k0 < KDIM; k0 += 32) {
        async16(Abase + k0,                     AldsU);
        async16(Abase + k0 + (size_t)64 * KDIM, AldsU + 2048);
        async16(Bbase + k0,                     BldsU);
        async16(Bbase + k0 + (size_t)64 * KDIM, BldsU + 2048);
        __syncthreads();

        bf16x8 af[4], bfv[4];
        #pragma unroll
        for (int mi = 0; mi < 4; ++mi) af[mi]  = *(const bf16x8*)(a_ptr + mi * 16 * 32);
        #pragma unroll
        for (int ni = 0; ni < 4; ++ni) bfv[ni] = *(const bf16x8*)(b_ptr + ni * 16 * 32);

        #pragma unroll
        for (int mi = 0; mi < 4; ++mi)
            #pragma unroll
            for (int ni = 0; ni < 4; ++ni)
                acc[mi][ni] = __builtin_amdgcn_mfma_f32_16x16x32_bf16(
                    af[mi], bfv[ni], acc[mi][ni], 0, 0, 0);
        __syncthreads();
    }

    // epilogue: lane holds D[row=(lane>>4)*4+r][col=lane&15] per 16x16 tile
    const int rb = wm + (lane >> 4) * 4;
    const int cb = wn + (lane & 15);
    float bv[4];
    #pragma unroll
    for (int ni = 0; ni < 4; ++ni) bv[ni] = bias[bn * 128 + cb + ni * 16];
    #pragma unroll
    for (int mi = 0; mi < 4; ++mi) {
        #pragma unroll
        for (int r = 0; r < 4; ++r) {
            size_t grow = (size_t)(bm * 128 + rb + mi * 16 + r) * NDIM;
            #pragma unroll
            for (int ni = 0; ni < 4; ++ni)
                C[grow + bn * 128 + cb + ni * 16] = f2bf(acc[mi][ni][r] + bv[ni]);
        }
    }
}

// ---------------------------------------------------------------------------
// block reduction of 4 floats across 256 threads (4 waves)
// ---------------------------------------------------------------------------
__device__ inline float4 block_reduce4(float a, float b, float c, float d, float* sm) {
    #pragma unroll
    for (int off = 32; off > 0; off >>= 1) {
        a += __shfl_down(a, off, 64);
        b += __shfl_down(b, off, 64);
        c += __shfl_down(c, off, 64);
        d += __shfl_down(d, off, 64);
    }
    int wid = threadIdx.x >> 6, lane = threadIdx.x & 63;
    __syncthreads();   // protect sm reuse
    if (lane == 0) {
        sm[wid * 4 + 0] = a; sm[wid * 4 + 1] = b;
        sm[wid * 4 + 2] = c; sm[wid * 4 + 3] = d;
    }
    __syncthreads();
    float4 r;
    r.x = sm[0] + sm[4] + sm[8]  + sm[12];
    r.y = sm[1] + sm[5] + sm[9]  + sm[13];
    r.z = sm[2] + sm[6] + sm[10] + sm[14];
    r.w = sm[3] + sm[7] + sm[11] + sm[15];
    return r;
}

// ---------------------------------------------------------------------------
// fused LN(hi) + LN(hh) + gates + LN(cell) + outputs. One block per row.
// thread t handles cols q*1024 + t*4 .. +4 for q=0..3 (the 4 gates align).
// ---------------------------------------------------------------------------
__global__ __launch_bounds__(256) void ln_gates(
    const unsigned short* __restrict__ hi_pre, const unsigned short* __restrict__ hh_pre,
    const float* __restrict__ c_prev,
    const float* __restrict__ g1, const float* __restrict__ be1,
    const float* __restrict__ g2, const float* __restrict__ be2,
    const float* __restrict__ gc, const float* __restrict__ bec,
    float* __restrict__ h_out, float* __restrict__ c_out)
{
    __shared__ float sm[16];
    const int b = blockIdx.x, t = threadIdx.x;
    const unsigned short* hir = hi_pre + (size_t)b * NDIM;
    const unsigned short* hhr = hh_pre + (size_t)b * NDIM;

    float xi[4][4], xh[4][4];
    float s1 = 0.f, ss1 = 0.f, s2 = 0.f, ss2 = 0.f;
    #pragma unroll
    for (int q = 0; q < 4; ++q) {
        int col = q * 1024 + t * 4;
        ushort4 ui = *(const ushort4*)(hir + col);
        ushort4 uh = *(const ushort4*)(hhr + col);
        xi[q][0] = bf2f(ui.x); xi[q][1] = bf2f(ui.y); xi[q][2] = bf2f(ui.z); xi[q][3] = bf2f(ui.w);
        xh[q][0] = bf2f(uh.x); xh[q][1] = bf2f(uh.y); xh[q][2] = bf2f(uh.z); xh[q][3] = bf2f(uh.w);
        #pragma unroll
        for (int j = 0; j < 4; ++j) {
            s1 += xi[q][j]; ss1 += xi[q][j] * xi[q][j];
            s2 += xh[q][j]; ss2 += xh[q][j] * xh[q][j];
        }
    }
    float4 red = block_reduce4(s1, ss1, s2, ss2, sm);
    const float n1 = (float)NDIM;
    float m1 = red.x / n1;
    float v1 = (red.y - n1 * m1 * m1) / (n1 - 1.f);
    float r1 = 1.0f / (sqrtf(fmaxf(v1, 0.f)) + EPSV);
    float m2 = red.z / n1;
    float v2 = (red.w - n1 * m2 * m2) / (n1 - 1.f);
    float r2 = 1.0f / (sqrtf(fmaxf(v2, 0.f)) + EPSV);

    // gates
    float gate[4][4];
    #pragma unroll
    for (int q = 0; q < 4; ++q) {
        int col = q * 1024 + t * 4;
        float4 G1 = *(const float4*)(g1 + col);
        float4 B1 = *(const float4*)(be1 + col);
        float4 G2 = *(const float4*)(g2 + col);
        float4 B2 = *(const float4*)(be2 + col);
        gate[q][0] = G1.x * (xi[q][0] - m1) * r1 + B1.x + G2.x * (xh[q][0] - m2) * r2 + B2.x;
        gate[q][1] = G1.y * (xi[q][1] - m1) * r1 + B1.y + G2.y * (xh[q][1] - m2) * r2 + B2.y;
        gate[q][2] = G1.z * (xi[q][2] - m1) * r1 + B1.z + G2.z * (xh[q][2] - m2) * r2 + B2.z;
        gate[q][3] = G1.w * (xi[q][3] - m1) * r1 + B1.w + G2.w * (xh[q][3] - m2) * r2 + B2.w;
    }

    float4 cp = *(const float4*)(c_prev + (size_t)b * 1024 + t * 4);
    float cpv[4] = {cp.x, cp.y, cp.z, cp.w};
    float a[4], og[4];
    float s3 = 0.f, ss3 = 0.f;
    #pragma unroll
    for (int j = 0; j < 4; ++j) {
        float ig = gate[0][j], fg = gate[1][j], ug = gate[2][j];
        og[j] = gate[3][j];
        a[j] = cpv[j] * sigm(fg + 1.0f) + ftanh(ug) * sigm(ig);
        s3 += a[j]; ss3 += a[j] * a[j];
    }
    float4 red2 = block_reduce4(s3, ss3, 0.f, 0.f, sm);
    const float n3 = 1024.f;
    float m3 = red2.x / n3;
    float v3 = (red2.y - n3 * m3 * m3) / (n3 - 1.f);
    float r3 = 1.0f / (sqrtf(fmaxf(v3, 0.f)) + EPSV);

    int colh = t * 4;
    float4 GC = *(const float4*)(gc + colh);
    float4 BC = *(const float4*)(bec + colh);
    float gcv[4] = {GC.x, GC.y, GC.z, GC.w};
    float bcv[4] = {BC.x, BC.y, BC.z, BC.w};
    float4 hv, cv;
    float cj[4], hj[4];
    #pragma unroll
    for (int j = 0; j < 4; ++j) {
        cj[j] = gcv[j] * (a[j] - m3) * r3 + bcv[j];
        hj[j] = sigm(og[j]) * ftanh(cj[j]);
    }
    hv.x = hj[0]; hv.y = hj[1]; hv.z = hj[2]; hv.w = hj[3];
    cv.x = cj[0]; cv.y = cj[1]; cv.z = cj[2]; cv.w = cj[3];
    *(float4*)(h_out + (size_t)b * 1024 + colh) = hv;
    *(float4*)(c_out + (size_t)b * 1024 + colh) = cv;
}

// ---------------------------------------------------------------------------
extern "C" void kernel_launch(void* const* d_in, const int* in_sizes, int n_in,
                              void* d_out, int out_size, void* d_ws, size_t ws_size,
                              hipStream_t stream) {
    const float* input  = (const float*)d_in[0];
    const float* h_prev = (const float*)d_in[1];
    const float* c_prev = (const float*)d_in[2];
    const float* w_i2h  = (const float*)d_in[3];
    const float* b_i2h  = (const float*)d_in[4];
    const float* w_h2h  = (const float*)d_in[5];
    const float* b_h2h  = (const float*)d_in[6];
    const float* g_i2h  = (const float*)d_in[7];
    const float* be_i2h = (const float*)d_in[8];
    const float* g_h2h  = (const float*)d_in[9];
    const float* be_h2h = (const float*)d_in[10];
    const float* g_c    = (const float*)d_in[11];
    const float* be_c   = (const float*)d_in[12];

    const size_t MK = (size_t)BDIM * KDIM;       // 4M
    const size_t MN = (size_t)BDIM * NDIM;       // 16M

    unsigned short* inA    = (unsigned short*)d_ws;
    unsigned short* inH    = inA + MK;
    unsigned short* w1T    = inH + MK;           // [N][K]
    unsigned short* w2T    = w1T + MK;
    unsigned short* hi_pre = w2T + MK;           // [B][4H] bf16
    unsigned short* hh_pre = hi_pre + MN;        // total 96 MB

    float* h_out = (float*)d_out;
    float* c_out = h_out + (size_t)BDIM * 1024;

    cast_bf16<<<dim3(4096, 1, 2), 256, 0, stream>>>(input, inA, h_prev, inH, (int)MK);
    transpose_cast<<<dim3(NDIM / 32, KDIM / 32, 2), dim3(32, 8), 0, stream>>>(
        w_i2h, w1T, w_h2h, w2T, KDIM, NDIM);

    gemm_bias_bf16<<<dim3(32, 32, 2), 256, 0, stream>>>(
        inA, w1T, b_i2h, hi_pre, inH, w2T, b_h2h, hh_pre);

    ln_gates<<<4096, 256, 0, stream>>>(
        hi_pre, hh_pre, c_prev, g_i2h, be_i2h, g_h2h, be_h2h, g_c, be_c, h_out, c_out);
}